// Round 2
// baseline (159.462 us; speedup 1.0000x reference)
//
#include <hip/hip_runtime.h>
#include <hip/hip_bf16.h>

// Word2Vec fused loss. M=4086 centers (pad 4096), V=32000 (pad 33280), D=128.
// loss = sum_i [ ln(sum_v 2^(l2_iv)) * ... ]  computed in exp2/log2 domain:
//   A stores bf16(ctx_mean * log2e); l2 = A.W (fp32 via MFMA); S = sum 2^l2
//   loss_i = ln2*log2(S_i) - tgt_i   (tgt in natural-log domain, fp32)

#define NCTR 4086
#define WIN 5
#define VOC 32000
#define DIM 128
#define MPAD 4096
#define VOCP 33280
#define LOG2E 1.44269504088896340736f
#define LN2 0.69314718055994530942f

typedef __attribute__((ext_vector_type(8))) __bf16 bf16x8;
typedef __attribute__((ext_vector_type(4))) __bf16 bf16x4;
typedef __attribute__((ext_vector_type(4))) float f32x4;

// ws layout (bytes):
//   [0,        8519680)  Wb    : bf16 VOCP*DIM (rows >= VOC zeroed)
//   [8519680,  9568256)  A     : bf16 MPAD*DIM (log2e-scaled ctx_mean; rows >= NCTR zero)
//   [9568256,  9584640)  expsum: float MPAD
//   [9584640,  9601024)  tgt   : float MPAD
#define WS_A      8519680
#define WS_EXPSUM 9568256
#define WS_TGT    9584640

#define NWCONV 4160   // VOCP*DIM/4/256 blocks for W->bf16 (+pad) part
#define NCTXB  2048   // MPAD/2 blocks for ctx part (2 rows per 256-thr block)

#if __has_builtin(__builtin_amdgcn_exp2f)
#define EXP2(x) __builtin_amdgcn_exp2f(x)
#else
#define EXP2(x) exp2f(x)
#endif

__global__ __launch_bounds__(256) void k_setup(const int* __restrict__ tokens,
                                               const float* __restrict__ emb,
                                               const float* __restrict__ W,
                                               __bf16* __restrict__ Wb,
                                               __bf16* __restrict__ A,
                                               float* __restrict__ tgt,
                                               float* __restrict__ expsum) {
    if (blockIdx.x < NWCONV) {
        // W (fp32) -> Wb (bf16), zero-pad rows >= VOC
        int i = blockIdx.x * 256 + threadIdx.x;   // 4 elements per thread
        bf16x4 o;
        if (i < VOC * DIM / 4) {
            f32x4 v = ((const f32x4*)W)[i];
            o.x = (__bf16)v.x; o.y = (__bf16)v.y; o.z = (__bf16)v.z; o.w = (__bf16)v.w;
        } else {
            o.x = o.y = o.z = o.w = (__bf16)0.0f;
        }
        ((bf16x4*)Wb)[i] = o;
        return;
    }
    // ctx part: 2 rows per block; threads [0,128) row0, [128,256) row1
    int i = (blockIdx.x - NWCONV) * 2 + (threadIdx.x >> 7);
    int d = threadIdx.x & 127;
    int half = threadIdx.x >> 7;
    if (d == 0) expsum[i] = 0.0f;
    __shared__ float red[4];
    if (i >= NCTR) {
        A[i * DIM + d] = (__bf16)0.0f;
        if (d == 0) tgt[i] = 0.0f;
        return;
    }
    int p = i + WIN;
    float s = 0.0f;
#pragma unroll
    for (int o = 1; o <= WIN; ++o) {
        s += emb[(long)tokens[p - o] * DIM + d];
        s += emb[(long)tokens[p + o] * DIM + d];
    }
    float m = s * 0.1f;
    A[i * DIM + d] = (__bf16)(m * LOG2E);
    float prod = m * W[(long)tokens[p] * DIM + d];   // natural domain target logit
#pragma unroll
    for (int off = 32; off; off >>= 1) prod += __shfl_down(prod, off);
    if ((threadIdx.x & 63) == 0) red[threadIdx.x >> 6] = prod;
    __syncthreads();
    if (d == 0) tgt[i] = red[half * 2] + red[half * 2 + 1];
}

// Per wave: 64 M-rows (4 x 16) held as A-frags in regs for the whole kernel;
// streams 26 steps of 16 N-cols with prefetch distance 2 (two B buffers).
// 80 streams (blockIdx.y*4 + wave) x 26 steps x 16 cols = 33280 padded rows.
__global__ __launch_bounds__(256, 3) void k_gemm(const __bf16* __restrict__ A,
                                                 const __bf16* __restrict__ Wb,
                                                 float* __restrict__ expsum) {
    const int lane = threadIdx.x & 63;
    const int wv   = threadIdx.x >> 6;
    const int lrow = lane & 15;
    const int quad = lane >> 4;
    const int m0   = blockIdx.x * 64;
    const int sid  = blockIdx.y * 4 + wv;       // 0..79
    const int STEP = 80 * 256;                  // bf16x8 units per col-step round

    // A-frags: A[m = m0+ms*16+lrow][k = kb*32 + quad*8 + j]
    const bf16x8* Ap = (const bf16x8*)A + (m0 + lrow) * 16 + quad;
    bf16x8 a[4][4];
#pragma unroll
    for (int ms = 0; ms < 4; ++ms)
#pragma unroll
        for (int kb = 0; kb < 4; ++kb)
            a[ms][kb] = Ap[ms * 256 + kb * 4];

    const bf16x8* Wp = (const bf16x8*)Wb + lrow * 16 + quad;
    int base = sid * 256;
    bf16x8 b0[4], b1[4];
#pragma unroll
    for (int kb = 0; kb < 4; ++kb) b0[kb] = Wp[base + kb * 4];
#pragma unroll
    for (int kb = 0; kb < 4; ++kb) b1[kb] = Wp[base + STEP + kb * 4];

    float run[4][4];
#pragma unroll
    for (int ms = 0; ms < 4; ++ms)
#pragma unroll
        for (int r = 0; r < 4; ++r) run[ms][r] = 0.0f;

    const f32x4 z = {0.0f, 0.0f, 0.0f, 0.0f};
    for (int i = 0; i < 13; ++i) {
        // ---- even step: consume b0, refill b0 <- t+2 ----
        {
            f32x4 acc[4];
#pragma unroll
            for (int ms = 0; ms < 4; ++ms) acc[ms] = z;
#pragma unroll
            for (int kb = 0; kb < 4; ++kb)
#pragma unroll
                for (int ms = 0; ms < 4; ++ms)
                    acc[ms] = __builtin_amdgcn_mfma_f32_16x16x32_bf16(a[ms][kb], b0[kb], acc[ms], 0, 0, 0);
#pragma unroll
            for (int kb = 0; kb < 4; ++kb) b0[kb] = Wp[base + 2 * STEP + kb * 4];
            // final-iter refills overread past Wb into A region: in-ws, values unused
#pragma unroll
            for (int ms = 0; ms < 4; ++ms)
#pragma unroll
                for (int r = 0; r < 4; ++r) run[ms][r] += EXP2(acc[ms][r]);
        }
        // ---- odd step: consume b1, refill b1 <- t+3 ----
        {
            f32x4 acc[4];
#pragma unroll
            for (int ms = 0; ms < 4; ++ms) acc[ms] = z;
#pragma unroll
            for (int kb = 0; kb < 4; ++kb)
#pragma unroll
                for (int ms = 0; ms < 4; ++ms)
                    acc[ms] = __builtin_amdgcn_mfma_f32_16x16x32_bf16(a[ms][kb], b1[kb], acc[ms], 0, 0, 0);
#pragma unroll
            for (int kb = 0; kb < 4; ++kb) b1[kb] = Wp[base + 3 * STEP + kb * 4];
#pragma unroll
            for (int ms = 0; ms < 4; ++ms)
#pragma unroll
                for (int r = 0; r < 4; ++r) run[ms][r] += EXP2(acc[ms][r]);
        }
        base += 2 * STEP;
    }

    // reduce across the 16 col-lanes, one atomic per row per wave
#pragma unroll
    for (int ms = 0; ms < 4; ++ms)
#pragma unroll
        for (int r = 0; r < 4; ++r) {
            float v = run[ms][r];
            v += __shfl_xor(v, 1);
            v += __shfl_xor(v, 2);
            v += __shfl_xor(v, 4);
            v += __shfl_xor(v, 8);
            if (lrow == 0) atomicAdd(&expsum[m0 + ms * 16 + quad * 4 + r], v);
        }
}

__global__ __launch_bounds__(256) void k_fin(const float* __restrict__ expsum,
                                             const float* __restrict__ tgt,
                                             float* __restrict__ out) {
    float s = 0.0f;
    for (int i = threadIdx.x; i < NCTR; i += 256)
        s += LN2 * __log2f(expsum[i]) - tgt[i];
#pragma unroll
    for (int off = 32; off; off >>= 1) s += __shfl_down(s, off);
    __shared__ float red[4];
    if ((threadIdx.x & 63) == 0) red[threadIdx.x >> 6] = s;
    __syncthreads();
    if (threadIdx.x == 0) out[0] = red[0] + red[1] + red[2] + red[3];
}

extern "C" void kernel_launch(void* const* d_in, const int* in_sizes, int n_in,
                              void* d_out, int out_size, void* d_ws, size_t ws_size,
                              hipStream_t stream) {
    const int*   tokens = (const int*)d_in[0];
    const float* emb    = (const float*)d_in[1];
    const float* W      = (const float*)d_in[2];
    float* out = (float*)d_out;
    char* ws = (char*)d_ws;
    __bf16* Wb     = (__bf16*)ws;
    __bf16* A      = (__bf16*)(ws + WS_A);
    float*  expsum = (float*)(ws + WS_EXPSUM);
    float*  tgt    = (float*)(ws + WS_TGT);

    k_setup<<<dim3(NWCONV + NCTXB), 256, 0, stream>>>(tokens, emb, W, Wb, A, tgt, expsum);
    k_gemm <<<dim3(64, 20), 256, 0, stream>>>(A, Wb, expsum);    // 1280 blocks
    k_fin  <<<dim3(1), 256, 0, stream>>>(expsum, tgt, out);
}

// Round 4
// 119.540 us; speedup vs baseline: 1.3340x; 1.3340x over previous
//
#include <hip/hip_runtime.h>
#include <hip/hip_bf16.h>

// Word2Vec fused loss. M=4086 centers (pad 4096), V=32000, D=128.
// exp2/log2 domain: A holds bf16(ctx_mean*log2e); per-row S = sum_v 2^(A.Wb_v);
// loss = sum_i [ LN2*log2(S_i) - tgt_i ].
//
// k_gemm: m97-style. Block = 128 M-rows x 4 waves; B staged 32 rows/step into
// LDS dbuf via global_load_lds (width 16, no VGPR landing), XOR-swizzled layout
// (baked into Wb) so ds_read_b128 of MFMA B-frags is bank-conflict-free.
// 40 streams x 25 steps x 32 rows = 32000 = V exactly.
// R3 fix: 8 KB tile needs TWO 16B-wide global_load_lds per wave per step
// (64 lanes x 16 B x 2 x 4 waves = 8 KB); R3 staged only half -> NaN.

#define NCTR 4086
#define WIN 5
#define VOC 32000
#define DIM 128
#define MPAD 4096
#define LOG2E 1.44269504088896340736f
#define LN2 0.69314718055994530942f

#define MT 128
#define NT 32
#define SSTR 40
#define TSTEP 25

typedef __attribute__((ext_vector_type(8))) __bf16 bf16x8;
typedef __attribute__((ext_vector_type(4))) float f32x4;

// ws layout (bytes):
//   [0,        8192000)  Wb : bf16 VOC*DIM, XOR-swizzled chunks within each row
//   [8192000,  9240576)  A  : bf16 MPAD*DIM plain row-major (log2e-scaled)
//   [9240576,  9256960)  expsum : float MPAD
//   [9256960,  9273344)  tgt    : float MPAD
#define WS_A      8192000
#define WS_EXPSUM 9240576
#define WS_TGT    9256960

#define NWCONV 2000   // VOC*16 chunk-units / 256
#define NCTXB  2048   // MPAD/2

#if __has_builtin(__builtin_amdgcn_exp2f)
#define EXP2(x) __builtin_amdgcn_exp2f(x)
#else
#define EXP2(x) exp2f(x)
#endif

#define GLOAD16(g, l) __builtin_amdgcn_global_load_lds(                         \
    (const __attribute__((address_space(1))) void*)(g),                         \
    (__attribute__((address_space(3))) void*)(l), 16, 0, 0)

__global__ __launch_bounds__(256) void k_setup(const int* __restrict__ tokens,
                                               const float* __restrict__ emb,
                                               const float* __restrict__ W,
                                               __bf16* __restrict__ Wb,
                                               __bf16* __restrict__ A,
                                               float* __restrict__ tgt,
                                               float* __restrict__ expsum) {
    if (blockIdx.x < NWCONV) {
        // W fp32 -> Wb bf16, 8 elems (one 16-B chunk) per thread, XOR-swizzled:
        // chunk c of row r lands at chunk position c ^ (r & 7).
        int id = blockIdx.x * 256 + threadIdx.x;   // (r, c) unit
        int r = id >> 4, c = id & 15;
        const f32x4* src = (const f32x4*)(W + (size_t)r * DIM + c * 8);
        f32x4 v0 = src[0], v1 = src[1];
        bf16x8 o;
        o[0] = (__bf16)v0.x; o[1] = (__bf16)v0.y; o[2] = (__bf16)v0.z; o[3] = (__bf16)v0.w;
        o[4] = (__bf16)v1.x; o[5] = (__bf16)v1.y; o[6] = (__bf16)v1.z; o[7] = (__bf16)v1.w;
        ((bf16x8*)Wb)[r * 16 + (c ^ (r & 7))] = o;
        return;
    }
    // ctx part: 2 rows per block; threads [0,128) row0, [128,256) row1
    int i = (blockIdx.x - NWCONV) * 2 + (threadIdx.x >> 7);
    int d = threadIdx.x & 127;
    int half = threadIdx.x >> 7;
    if (d == 0) expsum[i] = 0.0f;
    __shared__ float red[4];
    if (i >= NCTR) {
        A[i * DIM + d] = (__bf16)0.0f;
        if (d == 0) tgt[i] = 0.0f;
        return;
    }
    int p = i + WIN;
    float s = 0.0f;
#pragma unroll
    for (int o = 1; o <= WIN; ++o) {
        s += emb[(long)tokens[p - o] * DIM + d];
        s += emb[(long)tokens[p + o] * DIM + d];
    }
    float m = s * 0.1f;
    A[i * DIM + d] = (__bf16)(m * LOG2E);
    float prod = m * W[(long)tokens[p] * DIM + d];   // natural-log-domain target logit
#pragma unroll
    for (int off = 32; off; off >>= 1) prod += __shfl_down(prod, off);
    if ((threadIdx.x & 63) == 0) red[threadIdx.x >> 6] = prod;
    __syncthreads();
    if (d == 0) tgt[i] = red[half * 2] + red[half * 2 + 1];
}

// grid (32, 40): blockIdx.x = M-tile, blockIdx.y = N-stream.
__global__ __launch_bounds__(256) void k_gemm(const __bf16* __restrict__ A,
                                              const __bf16* __restrict__ Wb,
                                              float* __restrict__ expsum) {
    __shared__ __align__(16) __bf16 lds[2][NT * DIM];   // 2 x 8 KB
    const int tid  = threadIdx.x;
    const int lane = tid & 63;
    const int wv   = tid >> 6;
    const int lrow = lane & 15;
    const int quad = lane >> 4;
    const int m0   = blockIdx.x * MT;
    const int sid  = blockIdx.y;

    // A-frags: rows m0 + wv*32 + ms*16 + lrow, chunk kb*4+quad (plain layout)
    bf16x8 a[2][4];
    {
        const bf16x8* Ap = (const bf16x8*)A + (size_t)(m0 + wv * 32 + lrow) * 16 + quad;
#pragma unroll
        for (int ms = 0; ms < 2; ++ms)
#pragma unroll
            for (int kb = 0; kb < 4; ++kb)
                a[ms][kb] = Ap[ms * 256 + kb * 4];
    }

    float run[2][4];
#pragma unroll
    for (int ms = 0; ms < 2; ++ms)
#pragma unroll
        for (int r = 0; r < 4; ++r) run[ms][r] = 0.0f;

    // staging: step t covers Wb rows (t*SSTR + sid)*NT .. +NT (8 KB contiguous,
    // already swizzled in Wb). Wave wv copies its contiguous 2-KB slice with
    // TWO width-16 global_load_lds (each: 64 lanes x 16 B, deposit base+lane*16).
    const __bf16* gbase = Wb + (size_t)sid * NT * DIM + (size_t)wv * 1024 + (size_t)lane * 8;
    const int gstep = SSTR * NT * DIM;   // elems per step round

    GLOAD16(gbase,       &lds[0][wv * 1024]);
    GLOAD16(gbase + 512, &lds[0][wv * 1024 + 512]);

    for (int t = 0; t < TSTEP; ++t) {
        const int cur = t & 1;
        __syncthreads();   // drains staging of lds[cur] (vmcnt); prev compute done
        if (t + 1 < TSTEP) {
            const __bf16* gnext = gbase + (size_t)(t + 1) * gstep;
            GLOAD16(gnext,       &lds[cur ^ 1][wv * 1024]);
            GLOAD16(gnext + 512, &lds[cur ^ 1][wv * 1024 + 512]);
        }

        f32x4 acc[2][2];
        const f32x4 z = {0.0f, 0.0f, 0.0f, 0.0f};
#pragma unroll
        for (int ms = 0; ms < 2; ++ms) { acc[ms][0] = z; acc[ms][1] = z; }

#pragma unroll
        for (int kb = 0; kb < 4; ++kb) {
            // B-frag row nn*16+lrow, stored chunk (kb*4+quad) ^ (lrow&7)
            const int cs = (kb * 4 + quad) ^ (lrow & 7);
            bf16x8 b0 = *(const bf16x8*)&lds[cur][(lrow * 16 + cs) * 8];
            bf16x8 b1 = *(const bf16x8*)&lds[cur][((16 + lrow) * 16 + cs) * 8];
#pragma unroll
            for (int ms = 0; ms < 2; ++ms) {
                acc[ms][0] = __builtin_amdgcn_mfma_f32_16x16x32_bf16(a[ms][kb], b0, acc[ms][0], 0, 0, 0);
                acc[ms][1] = __builtin_amdgcn_mfma_f32_16x16x32_bf16(a[ms][kb], b1, acc[ms][1], 0, 0, 0);
            }
        }
#pragma unroll
        for (int ms = 0; ms < 2; ++ms)
#pragma unroll
            for (int r = 0; r < 4; ++r)
                run[ms][r] += EXP2(acc[ms][0][r]) + EXP2(acc[ms][1][r]);
    }

    // D layout: row m = quad*4 + r (within 16-tile), col = lrow. Reduce over the
    // 16 col-lanes (lane bits 0..3), then one atomic per row per wave.
#pragma unroll
    for (int ms = 0; ms < 2; ++ms)
#pragma unroll
        for (int r = 0; r < 4; ++r) {
            float v = run[ms][r];
            v += __shfl_xor(v, 1);
            v += __shfl_xor(v, 2);
            v += __shfl_xor(v, 4);
            v += __shfl_xor(v, 8);
            if (lrow == 0)
                atomicAdd(&expsum[m0 + wv * 32 + ms * 16 + quad * 4 + r], v);
        }
}

__global__ __launch_bounds__(1024) void k_fin(const float* __restrict__ expsum,
                                              const float* __restrict__ tgt,
                                              float* __restrict__ out) {
    int i = threadIdx.x;                 // 1024 threads x 4 elems = 4096
    f32x4 e = ((const f32x4*)expsum)[i];
    f32x4 g = ((const f32x4*)tgt)[i];
    float s = 0.0f;
#pragma unroll
    for (int c = 0; c < 4; ++c)
        if (i * 4 + c < NCTR) s += LN2 * __log2f(e[c]) - g[c];
#pragma unroll
    for (int off = 32; off; off >>= 1) s += __shfl_down(s, off);
    __shared__ float red[16];
    if ((i & 63) == 0) red[i >> 6] = s;
    __syncthreads();
    if (i == 0) {
        float tot = 0.0f;
#pragma unroll
        for (int w = 0; w < 16; ++w) tot += red[w];
        out[0] = tot;
    }
}

extern "C" void kernel_launch(void* const* d_in, const int* in_sizes, int n_in,
                              void* d_out, int out_size, void* d_ws, size_t ws_size,
                              hipStream_t stream) {
    const int*   tokens = (const int*)d_in[0];
    const float* emb    = (const float*)d_in[1];
    const float* W      = (const float*)d_in[2];
    float* out = (float*)d_out;
    char* ws = (char*)d_ws;
    __bf16* Wb     = (__bf16*)ws;
    __bf16* A      = (__bf16*)(ws + WS_A);
    float*  expsum = (float*)(ws + WS_EXPSUM);
    float*  tgt    = (float*)(ws + WS_TGT);

    k_setup<<<dim3(NWCONV + NCTXB), 256, 0, stream>>>(tokens, emb, W, Wb, A, tgt, expsum);
    k_gemm <<<dim3(32, SSTR), 256, 0, stream>>>(A, Wb, expsum);   // 1280 blocks
    k_fin  <<<dim3(1), 1024, 0, stream>>>(expsum, tgt, out);
}